// Round 17
// baseline (1013.275 us; speedup 1.0000x reference)
//
#include <hip/hip_runtime.h>
#include <hip/hip_bf16.h>
#include <math.h>

#define NN 8192
#define FIN 256
#define FOUT 64
#define LRELU_ALPHA 0.2f
#define TI 16          // rows per block (MFMA M)
#define TJ 256         // j-tile width
#define JS 8           // j-range split factor (r11-best: 4096 attn blocks)
#define JCHUNK (NN / JS)
#define NRB (NN / TI)  // 512 rowblocks

typedef __attribute__((ext_vector_type(8))) short short8v;
typedef __attribute__((ext_vector_type(4))) float f32x4;

static __device__ inline unsigned short f2bf(float f) {
  __hip_bfloat16 b = __float2bfloat16(f);   // HW cvt
  return *reinterpret_cast<unsigned short*>(&b);
}

// ---------------------------------------------------------------------------
// Fragment layouts (m89-verified family; validated by passing r4-r16):
//  16x16x32: A lane l: A[m=l&15][k=(l>>4)*8+e]; B: B[k=(l>>4)*8+e][n=l&15]
//            C/D: col=l&15, row=(l>>4)*4+reg
// WhF (bf16) for Wh[k][col]:
//  flat = ((k>>5)*4 + (col>>4))*512 + (((k>>3)&3)*16 + (col&15))*8 + (k&7)
// WF (bf16) for W[k][n]: frag (ks,nt): WF[(ks*4+nt)*512 + l*8 + e]
// p_lds (conflict-free both sides, r11-validated): for p[m][c]:
//  kt=c>>5, kg=(c>>3)&3, e=c&7, sw=(c>>3)&15
//  byte = kt*1024 + kg*256 + ((m ^ sw)<<4) + e*2
// ROUND 17 single change vs r11: comb kernel FUSED into attn via per-rowblock
// device-scope atomic counter; 8th-arriving block combines (fixed s-order sum
// -> deterministic). prep zeroes counters each call (atomicExch, replay-safe).
// ---------------------------------------------------------------------------

__global__ __launch_bounds__(256) void gat_prep(
    const float* __restrict__ W, const float* __restrict__ a,
    unsigned short* __restrict__ WF, float* __restrict__ wa1,
    float* __restrict__ wa2, int* __restrict__ cnt) {
  const int t = threadIdx.x;
  if (blockIdx.x < 8) {
    const int wid = blockIdx.x * 4 + (t >> 6);  // == ks*4 + nt
    const int ks = wid >> 2, nt = wid & 3;
    const int l = t & 63;
    const int kg = l >> 4, nn = l & 15;
    unsigned short frag[8];
#pragma unroll
    for (int e = 0; e < 8; ++e) {
      frag[e] = f2bf(W[(ks * 32 + kg * 8 + e) * FOUT + nt * 16 + nn]);
    }
    *(short8v*)&WF[wid * 512 + l * 8] = *(short8v*)frag;
  } else {
    float s1 = 0.f, s2 = 0.f;
#pragma unroll 4
    for (int c = 0; c < FOUT; c += 4) {
      const float4 wv = *(const float4*)&W[t * FOUT + c];
      const float4 a1 = *(const float4*)&a[c];
      const float4 a2 = *(const float4*)&a[FOUT + c];
      s1 += wv.x * a1.x + wv.y * a1.y + wv.z * a1.z + wv.w * a1.w;
      s2 += wv.x * a2.x + wv.y * a2.y + wv.z * a2.z + wv.w * a2.w;
    }
    wa1[t] = s1;
    wa2[t] = s2;
    // zero the per-rowblock arrival counters (device-scope, replay-safe)
    atomicExch(&cnt[t], 0);
    atomicExch(&cnt[t + 256], 0);
  }
}

__global__ __launch_bounds__(256) void gat_wh5(
    const float* __restrict__ h, const unsigned short* __restrict__ WF,
    const float* __restrict__ wa1, const float* __restrict__ wa2,
    unsigned short* __restrict__ WhF, float* __restrict__ Wh1,
    float* __restrict__ Wh2) {
  __shared__ __align__(16) float hs[TI][260];

  const int t = threadIdx.x;
  const int i0 = blockIdx.x * TI;

#pragma unroll
  for (int q = 0; q < 4; ++q) {
    const int idx = q * 256 + t;
    const float4 v = *(const float4*)&h[(size_t)i0 * FIN + (size_t)idx * 4];
    const int row = idx >> 6, col = (idx & 63) * 4;
    *(float4*)&hs[row][col] = v;
  }
  __syncthreads();

  {
    const int row = t >> 4, s = t & 15;
    float p1 = 0.f, p2 = 0.f;
#pragma unroll
    for (int q = 0; q < 16; ++q) {
      const int k = s + q * 16;
      const float hv = hs[row][k];
      p1 = fmaf(hv, wa1[k], p1);
      p2 = fmaf(hv, wa2[k], p2);
    }
#pragma unroll
    for (int off = 8; off; off >>= 1) {
      p1 += __shfl_xor(p1, off);
      p2 += __shfl_xor(p2, off);
    }
    if (s == 0) {
      Wh1[i0 + row] = p1;
      Wh2[i0 + row] = p2;
    }
  }

  const int w = t >> 6, l = t & 63;
  const int kg = l >> 4, m = l & 15;
  f32x4 acc = {0.f, 0.f, 0.f, 0.f};
#pragma unroll
  for (int ks = 0; ks < 8; ++ks) {
    const float4 fa = *(const float4*)&hs[m][ks * 32 + kg * 8];
    const float4 fb = *(const float4*)&hs[m][ks * 32 + kg * 8 + 4];
    unsigned short af[8];
    af[0] = f2bf(fa.x); af[1] = f2bf(fa.y);
    af[2] = f2bf(fa.z); af[3] = f2bf(fa.w);
    af[4] = f2bf(fb.x); af[5] = f2bf(fb.y);
    af[6] = f2bf(fb.z); af[7] = f2bf(fb.w);
    const short8v bf = *(const short8v*)&WF[(ks * 4 + w) * 512 + l * 8];
    acc =
        __builtin_amdgcn_mfma_f32_16x16x32_bf16(*(short8v*)af, bf, acc, 0, 0, 0);
  }

  const int k0 = i0 + kg * 4;
  const int col = w * 16 + m;
  const int basef = ((k0 >> 5) * 4 + (col >> 4)) * 512 +
                    (((k0 >> 3) & 3) * 16 + (col & 15)) * 8 + (k0 & 7);
  ushort4 st;
  st.x = f2bf(acc[0]);
  st.y = f2bf(acc[1]);
  st.z = f2bf(acc[2]);
  st.w = f2bf(acc[3]);
  *(ushort4*)&WhF[basef] = st;
}

// ---------------------------------------------------------------------------
// gat_attn10: r11's attn6 + fused last-block combine (the only change).
// ---------------------------------------------------------------------------
__global__ __launch_bounds__(256) void gat_attn10(
    const int* __restrict__ adj, const unsigned short* __restrict__ WhF,
    const float* __restrict__ Wh1, const float* __restrict__ Wh2,
    float* __restrict__ num, float* __restrict__ den, int* __restrict__ cnt,
    float* __restrict__ out) {
  __shared__ __align__(16) unsigned short p_lds[2][TI * TJ];  // 2 x 8 KB
  __shared__ float den_lds[TI];
  __shared__ int lastflag;

  const int t = threadIdx.x;
  const int jsplit = blockIdx.x & (JS - 1);
  const int rb = blockIdx.x >> 3;          // rowblock, JS == 8
  const int i0 = rb * TI;
  const int j0 = jsplit * JCHUNK;

  const int r0 = t >> 5;
  const int col8 = (t & 31) * 8;
  const float w1_0 = Wh1[i0 + r0];
  const float w1_1 = Wh1[i0 + r0 + 8];

  const int w = t >> 6;
  const int l = t & 63;
  const int arow = l & 15;
  const int kg = l >> 4;
  const int colw = w * 16 + arow;

  float ds0 = 0.f, ds1 = 0.f;
  f32x4 acc = {0.f, 0.f, 0.f, 0.f};

  const int wkt = (t & 31) >> 2, wkg = t & 3, wsw = t & 15;
  const int wr0 = wkt * 1024 + wkg * 256 + (((r0 ^ wsw) & 15) << 4);
  const int wr1 = wr0 ^ 128;

  int4 a00, a01, a10, a11;
  float4 w2a, w2b;
  {
    const int4* ap0 = (const int4*)&adj[(size_t)(i0 + r0) * NN + j0 + col8];
    const int4* ap1 = (const int4*)&adj[(size_t)(i0 + r0 + 8) * NN + j0 + col8];
    a00 = ap0[0]; a01 = ap0[1];
    a10 = ap1[0]; a11 = ap1[1];
    w2a = *(const float4*)&Wh2[j0 + col8];
    w2b = *(const float4*)&Wh2[j0 + col8 + 4];
  }

  for (int jb = j0, it = 0; jb < j0 + JCHUNK; jb += TJ, ++it) {
    unsigned short* pl = &p_lds[it & 1][0];

    const float w2v[8] = {w2a.x, w2a.y, w2a.z, w2a.w,
                          w2b.x, w2b.y, w2b.z, w2b.w};
    const int am0[8] = {a00.x, a00.y, a00.z, a00.w, a01.x, a01.y, a01.z, a01.w};
    const int am1[8] = {a10.x, a10.y, a10.z, a10.w, a11.x, a11.y, a11.z, a11.w};

    short8v pv0, pv1;
#pragma unroll
    for (int e = 0; e < 8; ++e) {
      float v0 = w1_0 + w2v[e];
      v0 = v0 > 0.f ? v0 : LRELU_ALPHA * v0;
      float p0 = (am0[e] > 0) ? __expf(v0) : 0.f;
      ds0 += p0;
      pv0[e] = (short)f2bf(p0);
      float v1 = w1_1 + w2v[e];
      v1 = v1 > 0.f ? v1 : LRELU_ALPHA * v1;
      float p1 = (am1[e] > 0) ? __expf(v1) : 0.f;
      ds1 += p1;
      pv1[e] = (short)f2bf(p1);
    }
    *(short8v*)((char*)pl + wr0) = pv0;
    *(short8v*)((char*)pl + wr1) = pv1;

    if (jb + TJ < j0 + JCHUNK) {
      const int jn = jb + TJ;
      const int4* ap0 = (const int4*)&adj[(size_t)(i0 + r0) * NN + jn + col8];
      const int4* ap1 =
          (const int4*)&adj[(size_t)(i0 + r0 + 8) * NN + jn + col8];
      a00 = ap0[0]; a01 = ap0[1];
      a10 = ap1[0]; a11 = ap1[1];
      w2a = *(const float4*)&Wh2[jn + col8];
      w2b = *(const float4*)&Wh2[jn + col8 + 4];
    }

    asm volatile("s_waitcnt lgkmcnt(0)" ::: "memory");
    __builtin_amdgcn_sched_barrier(0);
    __builtin_amdgcn_s_barrier();

    const int kblk0 = jb >> 5;
#pragma unroll
    for (int kt = 0; kt < 8; ++kt) {
      const int swk = (kt * 4 + kg) & 15;
      const int raddr = kt * 1024 + (kg << 8) + ((arow ^ swk) << 4);
      short8v af = *(const short8v*)((const char*)pl + raddr);
      short8v bf = *(const short8v*)&WhF[((kblk0 + kt) * 4 + w) * 512 + l * 8];
      acc = __builtin_amdgcn_mfma_f32_16x16x32_bf16(af, bf, acc, 0, 0, 0);
    }
  }

  // den: half-wave shfl reduce, rows disjoint across waves
#pragma unroll
  for (int off = 16; off; off >>= 1) {
    ds0 += __shfl_xor(ds0, off);
    ds1 += __shfl_xor(ds1, off);
  }
  if ((t & 31) == 0) {
    const int rr = t >> 5;
    den_lds[rr] = ds0;
    den_lds[rr + 8] = ds1;
  }
  __syncthreads();
  if (t < TI) den[(size_t)jsplit * NN + i0 + t] = den_lds[t];

  // num partial: C/D layout col=l&15, row=(l>>4)*4+reg
#pragma unroll
  for (int r = 0; r < 4; ++r) {
    num[((size_t)jsplit * NN + i0 + kg * 4 + r) * FOUT + colw] = acc[r];
  }

  // ---- fused combine: 8th-arriving block for this rowblock finishes ----
  __threadfence();          // release: drain this thread's partial stores
  __syncthreads();          // all threads' stores fenced
  if (t == 0) {
    const int old = atomicAdd(&cnt[rb], 1);
    lastflag = (old == JS - 1);
  }
  __syncthreads();
  if (lastflag) {
    __threadfence();        // acquire: see other blocks' partials
#pragma unroll
    for (int q = 0; q < 4; ++q) {
      const int idx = q * 256 + t;            // 0..1023 = 16 rows x 64 cols
      const int row = idx >> 6, oc = idx & 63;
      float n = 0.f, d = 0.f;
#pragma unroll
      for (int s = 0; s < JS; ++s) {          // fixed order -> deterministic
        n += num[((size_t)s * NN + i0 + row) * FOUT + oc];
        d += den[(size_t)s * NN + i0 + row];
      }
      const float v = n / d;
      out[(size_t)(i0 + row) * FOUT + oc] = v > 0.f ? v : expm1f(v);
    }
  }
}

extern "C" void kernel_launch(void* const* d_in, const int* in_sizes, int n_in,
                              void* d_out, int out_size, void* d_ws,
                              size_t ws_size, hipStream_t stream) {
  const float* h = (const float*)d_in[0];
  const int* adj = (const int*)d_in[1];
  const float* W = (const float*)d_in[2];
  const float* a = (const float*)d_in[3];
  float* out = (float*)d_out;

  unsigned short* WhF = (unsigned short*)d_ws;          // 1 MB bf16 fragments
  float* Wh1 = (float*)((char*)d_ws + (1 << 20));       // 32 KB
  float* Wh2 = Wh1 + NN;                                // 32 KB
  float* num = (float*)((char*)d_ws + (2 << 20));       // 16 MB
  float* den = num + (size_t)JS * NN * FOUT;            // 256 KB
  int* cnt = (int*)(den + (size_t)JS * NN);             // 2 KB (512 counters)
  unsigned short* WF = (unsigned short*)((char*)d_ws + (24u << 20));  // 32 KB
  float* wa1 = (float*)((char*)d_ws + (24u << 20) + (64u << 10));     // 1 KB
  float* wa2 = wa1 + FIN;                                             // 1 KB

  gat_prep<<<9, 256, 0, stream>>>(W, a, WF, wa1, wa2, cnt);
  gat_wh5<<<NN / TI, 256, 0, stream>>>(h, WF, wa1, wa2, WhF, Wh1, Wh2);
  gat_attn10<<<(NN / TI) * JS, 256, 0, stream>>>(adj, WhF, Wh1, Wh2, num, den,
                                                 cnt, out);
}

// Round 18
// 80.464 us; speedup vs baseline: 12.5930x; 12.5930x over previous
//
#include <hip/hip_runtime.h>
#include <hip/hip_bf16.h>
#include <math.h>

#define NN 8192
#define FIN 256
#define FOUT 64
#define LRELU_ALPHA 0.2f
#define TI 16          // rows per block (MFMA M)
#define TJ 256         // j-tile width
#define JS 8           // j-range split factor (best: 4096 attn blocks)
#define JCHUNK (NN / JS)

typedef __attribute__((ext_vector_type(8))) short short8v;
typedef __attribute__((ext_vector_type(4))) float f32x4;

static __device__ inline unsigned short f2bf(float f) {
  __hip_bfloat16 b = __float2bfloat16(f);   // HW cvt
  return *reinterpret_cast<unsigned short*>(&b);
}

// ---------------------------------------------------------------------------
// FINAL (r11-best, 80.2 us): restored verbatim after 6 regressing probes:
//  exp-free separable (+3.7), JS=4 (+8.4), launch_bounds(,6) spills (+36),
//  depth-2 adj prefetch (+3.0), fused last-block combine w/ threadfence
//  (+933: per-block device fence = L2 writeback x4096 -- never do this).
// attn moves the mandatory cold 268MB adj at ~84% of copy ceiling with all
// compute hidden under the stream; practical plateau for this decomposition.
//
// Fragment layouts (m89-verified family; validated by passing r4-r17):
//  16x16x32: A lane l: A[m=l&15][k=(l>>4)*8+e]; B: B[k=(l>>4)*8+e][n=l&15]
//            C/D: col=l&15, row=(l>>4)*4+reg
// WhF (bf16) for Wh[k][col]:
//  flat = ((k>>5)*4 + (col>>4))*512 + (((k>>3)&3)*16 + (col&15))*8 + (k&7)
// WF (bf16) for W[k][n]: frag (ks,nt): WF[(ks*4+nt)*512 + l*8 + e]
// p_lds (conflict-free both sides): for p[m][c]:
//  kt=c>>5, kg=(c>>3)&3, e=c&7, sw=(c>>3)&15
//  byte = kt*1024 + kg*256 + ((m ^ sw)<<4) + e*2
// ---------------------------------------------------------------------------

__global__ __launch_bounds__(256) void gat_prep(
    const float* __restrict__ W, const float* __restrict__ a,
    unsigned short* __restrict__ WF, float* __restrict__ wa1,
    float* __restrict__ wa2) {
  const int t = threadIdx.x;
  if (blockIdx.x < 8) {
    const int wid = blockIdx.x * 4 + (t >> 6);  // == ks*4 + nt
    const int ks = wid >> 2, nt = wid & 3;
    const int l = t & 63;
    const int kg = l >> 4, nn = l & 15;
    unsigned short frag[8];
#pragma unroll
    for (int e = 0; e < 8; ++e) {
      frag[e] = f2bf(W[(ks * 32 + kg * 8 + e) * FOUT + nt * 16 + nn]);
    }
    *(short8v*)&WF[wid * 512 + l * 8] = *(short8v*)frag;
  } else {
    float s1 = 0.f, s2 = 0.f;
#pragma unroll 4
    for (int c = 0; c < FOUT; c += 4) {
      const float4 wv = *(const float4*)&W[t * FOUT + c];
      const float4 a1 = *(const float4*)&a[c];
      const float4 a2 = *(const float4*)&a[FOUT + c];
      s1 += wv.x * a1.x + wv.y * a1.y + wv.z * a1.z + wv.w * a1.w;
      s2 += wv.x * a2.x + wv.y * a2.y + wv.z * a2.z + wv.w * a2.w;
    }
    wa1[t] = s1;
    wa2[t] = s2;
  }
}

__global__ __launch_bounds__(256) void gat_wh5(
    const float* __restrict__ h, const unsigned short* __restrict__ WF,
    const float* __restrict__ wa1, const float* __restrict__ wa2,
    unsigned short* __restrict__ WhF, float* __restrict__ Wh1,
    float* __restrict__ Wh2) {
  __shared__ __align__(16) float hs[TI][260];

  const int t = threadIdx.x;
  const int i0 = blockIdx.x * TI;

#pragma unroll
  for (int q = 0; q < 4; ++q) {
    const int idx = q * 256 + t;
    const float4 v = *(const float4*)&h[(size_t)i0 * FIN + (size_t)idx * 4];
    const int row = idx >> 6, col = (idx & 63) * 4;
    *(float4*)&hs[row][col] = v;
  }
  __syncthreads();

  {
    const int row = t >> 4, s = t & 15;
    float p1 = 0.f, p2 = 0.f;
#pragma unroll
    for (int q = 0; q < 16; ++q) {
      const int k = s + q * 16;
      const float hv = hs[row][k];
      p1 = fmaf(hv, wa1[k], p1);
      p2 = fmaf(hv, wa2[k], p2);
    }
#pragma unroll
    for (int off = 8; off; off >>= 1) {
      p1 += __shfl_xor(p1, off);
      p2 += __shfl_xor(p2, off);
    }
    if (s == 0) {
      Wh1[i0 + row] = p1;
      Wh2[i0 + row] = p2;
    }
  }

  const int w = t >> 6, l = t & 63;
  const int kg = l >> 4, m = l & 15;
  f32x4 acc = {0.f, 0.f, 0.f, 0.f};
#pragma unroll
  for (int ks = 0; ks < 8; ++ks) {
    const float4 fa = *(const float4*)&hs[m][ks * 32 + kg * 8];
    const float4 fb = *(const float4*)&hs[m][ks * 32 + kg * 8 + 4];
    unsigned short af[8];
    af[0] = f2bf(fa.x); af[1] = f2bf(fa.y);
    af[2] = f2bf(fa.z); af[3] = f2bf(fa.w);
    af[4] = f2bf(fb.x); af[5] = f2bf(fb.y);
    af[6] = f2bf(fb.z); af[7] = f2bf(fb.w);
    const short8v bf = *(const short8v*)&WF[(ks * 4 + w) * 512 + l * 8];
    acc =
        __builtin_amdgcn_mfma_f32_16x16x32_bf16(*(short8v*)af, bf, acc, 0, 0, 0);
  }

  const int k0 = i0 + kg * 4;
  const int col = w * 16 + m;
  const int basef = ((k0 >> 5) * 4 + (col >> 4)) * 512 +
                    (((k0 >> 3) & 3) * 16 + (col & 15)) * 8 + (k0 & 7);
  ushort4 st;
  st.x = f2bf(acc[0]);
  st.y = f2bf(acc[1]);
  st.z = f2bf(acc[2]);
  st.w = f2bf(acc[3]);
  *(ushort4*)&WhF[basef] = st;
}

// ---------------------------------------------------------------------------
// gat_attn6: coalesced adj -> fragment-ordered p_lds -> MFMA; lgkm-only raw
// barrier (vmcnt loads ride across); depth-1 reg prefetch; JS=8.
// ---------------------------------------------------------------------------
__global__ __launch_bounds__(256) void gat_attn6(
    const int* __restrict__ adj, const unsigned short* __restrict__ WhF,
    const float* __restrict__ Wh1, const float* __restrict__ Wh2,
    float* __restrict__ num, float* __restrict__ den) {
  __shared__ __align__(16) unsigned short p_lds[2][TI * TJ];  // 2 x 8 KB
  __shared__ float den_lds[TI];

  const int t = threadIdx.x;
  const int jsplit = blockIdx.x & (JS - 1);
  const int i0 = (blockIdx.x >> 3) * TI;   // JS == 8
  const int j0 = jsplit * JCHUNK;

  const int r0 = t >> 5;
  const int col8 = (t & 31) * 8;
  const float w1_0 = Wh1[i0 + r0];
  const float w1_1 = Wh1[i0 + r0 + 8];

  const int w = t >> 6;
  const int l = t & 63;
  const int arow = l & 15;
  const int kg = l >> 4;
  const int colw = w * 16 + arow;

  float ds0 = 0.f, ds1 = 0.f;
  f32x4 acc = {0.f, 0.f, 0.f, 0.f};

  const int wkt = (t & 31) >> 2, wkg = t & 3, wsw = t & 15;
  const int wr0 = wkt * 1024 + wkg * 256 + (((r0 ^ wsw) & 15) << 4);
  const int wr1 = wr0 ^ 128;

  int4 a00, a01, a10, a11;
  float4 w2a, w2b;
  {
    const int4* ap0 = (const int4*)&adj[(size_t)(i0 + r0) * NN + j0 + col8];
    const int4* ap1 = (const int4*)&adj[(size_t)(i0 + r0 + 8) * NN + j0 + col8];
    a00 = ap0[0]; a01 = ap0[1];
    a10 = ap1[0]; a11 = ap1[1];
    w2a = *(const float4*)&Wh2[j0 + col8];
    w2b = *(const float4*)&Wh2[j0 + col8 + 4];
  }

  for (int jb = j0, it = 0; jb < j0 + JCHUNK; jb += TJ, ++it) {
    unsigned short* pl = &p_lds[it & 1][0];

    const float w2v[8] = {w2a.x, w2a.y, w2a.z, w2a.w,
                          w2b.x, w2b.y, w2b.z, w2b.w};
    const int am0[8] = {a00.x, a00.y, a00.z, a00.w, a01.x, a01.y, a01.z, a01.w};
    const int am1[8] = {a10.x, a10.y, a10.z, a10.w, a11.x, a11.y, a11.z, a11.w};

    short8v pv0, pv1;
#pragma unroll
    for (int e = 0; e < 8; ++e) {
      float v0 = w1_0 + w2v[e];
      v0 = v0 > 0.f ? v0 : LRELU_ALPHA * v0;
      float p0 = (am0[e] > 0) ? __expf(v0) : 0.f;
      ds0 += p0;
      pv0[e] = (short)f2bf(p0);
      float v1 = w1_1 + w2v[e];
      v1 = v1 > 0.f ? v1 : LRELU_ALPHA * v1;
      float p1 = (am1[e] > 0) ? __expf(v1) : 0.f;
      ds1 += p1;
      pv1[e] = (short)f2bf(p1);
    }
    *(short8v*)((char*)pl + wr0) = pv0;
    *(short8v*)((char*)pl + wr1) = pv1;

    if (jb + TJ < j0 + JCHUNK) {
      const int jn = jb + TJ;
      const int4* ap0 = (const int4*)&adj[(size_t)(i0 + r0) * NN + jn + col8];
      const int4* ap1 =
          (const int4*)&adj[(size_t)(i0 + r0 + 8) * NN + jn + col8];
      a00 = ap0[0]; a01 = ap0[1];
      a10 = ap1[0]; a11 = ap1[1];
      w2a = *(const float4*)&Wh2[jn + col8];
      w2b = *(const float4*)&Wh2[jn + col8 + 4];
    }

    asm volatile("s_waitcnt lgkmcnt(0)" ::: "memory");
    __builtin_amdgcn_sched_barrier(0);
    __builtin_amdgcn_s_barrier();

    const int kblk0 = jb >> 5;
#pragma unroll
    for (int kt = 0; kt < 8; ++kt) {
      const int swk = (kt * 4 + kg) & 15;
      const int raddr = kt * 1024 + (kg << 8) + ((arow ^ swk) << 4);
      short8v af = *(const short8v*)((const char*)pl + raddr);
      short8v bf = *(const short8v*)&WhF[((kblk0 + kt) * 4 + w) * 512 + l * 8];
      acc = __builtin_amdgcn_mfma_f32_16x16x32_bf16(af, bf, acc, 0, 0, 0);
    }
  }

#pragma unroll
  for (int off = 16; off; off >>= 1) {
    ds0 += __shfl_xor(ds0, off);
    ds1 += __shfl_xor(ds1, off);
  }
  if ((t & 31) == 0) {
    const int rr = t >> 5;
    den_lds[rr] = ds0;
    den_lds[rr + 8] = ds1;
  }
  __syncthreads();
  if (t < TI) den[(size_t)jsplit * NN + i0 + t] = den_lds[t];

#pragma unroll
  for (int r = 0; r < 4; ++r) {
    num[((size_t)jsplit * NN + i0 + kg * 4 + r) * FOUT + colw] = acc[r];
  }
}

__global__ __launch_bounds__(256) void gat_comb(
    const float* __restrict__ num, const float* __restrict__ den,
    float* __restrict__ out) {
  const int idx = blockIdx.x * 256 + threadIdx.x;
  const int row = idx >> 6;
  float n = 0.f, d = 0.f;
#pragma unroll
  for (int s = 0; s < JS; ++s) {
    n += num[(size_t)s * NN * FOUT + idx];
    d += den[(size_t)s * NN + row];
  }
  float v = n / d;
  out[idx] = v > 0.f ? v : expm1f(v);
}

extern "C" void kernel_launch(void* const* d_in, const int* in_sizes, int n_in,
                              void* d_out, int out_size, void* d_ws,
                              size_t ws_size, hipStream_t stream) {
  const float* h = (const float*)d_in[0];
  const int* adj = (const int*)d_in[1];
  const float* W = (const float*)d_in[2];
  const float* a = (const float*)d_in[3];
  float* out = (float*)d_out;

  unsigned short* WhF = (unsigned short*)d_ws;          // 1 MB bf16 fragments
  float* Wh1 = (float*)((char*)d_ws + (1 << 20));       // 32 KB
  float* Wh2 = Wh1 + NN;                                // 32 KB
  float* num = (float*)((char*)d_ws + (2 << 20));       // 16 MB
  float* den = num + (size_t)JS * NN * FOUT;            // 256 KB
  unsigned short* WF = (unsigned short*)((char*)d_ws + (24u << 20));  // 32 KB
  float* wa1 = (float*)((char*)d_ws + (24u << 20) + (64u << 10));     // 1 KB
  float* wa2 = wa1 + FIN;                                             // 1 KB

  gat_prep<<<9, 256, 0, stream>>>(W, a, WF, wa1, wa2);
  gat_wh5<<<NN / TI, 256, 0, stream>>>(h, WF, wa1, wa2, WhF, Wh1, Wh2);
  gat_attn6<<<(NN / TI) * JS, 256, 0, stream>>>(adj, WhF, Wh1, Wh2, num, den);
  gat_comb<<<NN * FOUT / 256, 256, 0, stream>>>(num, den, out);
}